// Round 7
// baseline (424060.645 us; speedup 1.0000x reference)
//
#include <hip/hip_runtime.h>
#include <math.h>

// BiLSTM B=64, S=512, I=H=512, fp32 in/out.
// Gate order f,g,i,o:  c = c*sig(f) + tanh(g)*sig(i); h = sig(o)*tanh(c)
// mask all-ones => lengths==S, h_f = fwd[S-1], h_b = bwd[0].
//
// Round-9 design: persistent kernel with XCD-LOCAL sync groups + L2 coherence.
//   Round-6 (2484us) spent ~4 x ~2000cy per step on L3-coherence hops (sc0 sc1).
//   This round moves the coherence point to the per-XCD L2:
//   - 8 groups = (d, batch-quarter mq); group g = blk&7 -> all 16 blocks of a
//     group land on XCD g (round-robin dispatch heuristic, m09/m157).
//   - h-ring/flag stores+loads use sc0 ONLY (bypass L1, served by shared L2):
//     RTT ~300cy instead of ~2000cy.
//   - h slab (16KB/group) de-duplicated: per block ONE reg-staged load -> LDS;
//     8 waves read A-fragments from LDS (round-5 idea, viable at L2 latency).
//   - blocks: 128 x 512 thr (8 waves, 1 block/CU); wave owns one 16-col n-tile,
//     one 16-batch m-tile; 32 MFMAs/step/wave, even/odd K chains for ILP-2.
//   - x path unchanged from round 6 (pre-swizzled bf16 tiles + global_load_lds,
//     raw barriers + counted/poll-drained vmcnt; x-MFMA for t+1 in the tail).
//   - producer chain pristine (round-4 lesson): pack -> sc0 store -> vmcnt(0)
//     -> flag, nothing else queued.
//   FAILURE MODE if blk%8 != XCD: flag stays dirty in a foreign L2 -> watchdog
//   (2^13 polls) breaks -> wrong results -> fails LOUD (no hang, no wedge).

#define Sd 512
#define Bd 64
#define Hd 512
#define TWO_H 1024

typedef __attribute__((ext_vector_type(8))) short bf16x8;
typedef __attribute__((ext_vector_type(4))) float f32x4;

// ws layout (bytes)
#define UWT_OFF   0u          // bf16 [2][128][32][64][8]  = 8,388,608 B
#define BIAS_OFF  8388608u    // f32  [2][2048]            = 16,384 B
#define HBF_OFF   8404992u    // bf16 [2p][8g][16kb][64][8] = 262,144 B
#define FLG_OFF   8667136u    // u32  [8 groups][64] flags = 2,048 B
#define XT_OFF    8669184u    // bf16 tiles [4mq][512t][1024 frag][16B] = 33,554,432 B
#define WS_NEED   (XT_OFF + 33554432u)

__device__ __forceinline__ unsigned short f2bf(float f) {
    unsigned u = __float_as_uint(f);
    u += 0x7fffu + ((u >> 16) & 1u);   // round-to-nearest-even
    return (unsigned short)(u >> 16);
}
__device__ __forceinline__ float sigmoidf_(float v) { return 1.0f / (1.0f + __expf(-v)); }
__device__ __forceinline__ float tanhf_(float v) {
    const float e = __expf(2.0f * v);  // exact at +/-inf
    return 1.0f - 2.0f / (e + 1.0f);
}
__device__ __forceinline__ unsigned cvt_pk_bf16(float lo, float hi) {
    unsigned r;
    asm("v_cvt_pk_bf16_f32 %0, %1, %2" : "=v"(r) : "v"(lo), "v"(hi));
    return r;
}
__device__ __forceinline__ void gld_lds16(const void* g, void* l) {
    __builtin_amdgcn_global_load_lds(
        (const __attribute__((address_space(1))) void*)(g),
        (__attribute__((address_space(3))) void*)(l), 16, 0, 0);
}
__device__ __forceinline__ void raw_bar() {
    __builtin_amdgcn_sched_barrier(0);
    __builtin_amdgcn_s_barrier();
    __builtin_amdgcn_sched_barrier(0);
}
__device__ __forceinline__ void lgkm_bar() {
    asm volatile("s_waitcnt lgkmcnt(0)" ::: "memory");
    raw_bar();
}

// L2-scope (same-XCD) coherent 16B load: bypass L1 only
#define LDC16(dst, ptr)                                                 \
    asm volatile("global_load_dwordx4 %0, %1, off sc0"                  \
                 : "=&v"(dst) : "v"(ptr))

// ---------------- prep: weights -> swizzled bf16 B-operand layout ----------------
__global__ __launch_bounds__(256) void prep_weights(
    const float* __restrict__ U_f, const float* __restrict__ W_f,
    const float* __restrict__ U_b, const float* __restrict__ W_b,
    unsigned short* __restrict__ uwt)
{
    const unsigned i = blockIdx.x * 256u + threadIdx.x;   // 524,288 threads
    const int h   = i & 511;
    const int k8  = (i >> 9) & 63;
    const int g   = (i >> 15) & 3;
    const int mat = (i >> 17) & 1;
    const int d   = (i >> 18) & 1;

    const float* src = mat ? (d ? W_b : W_f) : (d ? U_b : U_f);
    src += (size_t)g * Hd * Hd + (size_t)(k8 * 8) * Hd + h;

    const int n    = h * 4 + g;                      // gate-interleaved column
    const int nt   = n >> 4;
    const int lane = (n & 15) + ((mat * 64 + k8) & 3) * 16;
    const int kb   = mat * 16 + (k8 >> 2);

    bf16x8 v;
    #pragma unroll
    for (int j = 0; j < 8; ++j)
        v[j] = (short)f2bf(src[(size_t)j * Hd]);

    ((bf16x8*)uwt)[((d * 128 + nt) * 32 + kb) * 64 + lane] = v;
}

// ---------------- prep: x fp32 -> bf16 fragment-swizzled tiles ----------------
// tile (mq, t): 1024 fragments of 16B; fragment v = m*64 + ((kb*4+q)^(m&7))
// holds x[b=mq*16+m][t][kb*32+q*8 .. +8) as bf16. Linear = gload_lds-ready.
__global__ __launch_bounds__(256) void prep_x(
    const float* __restrict__ x, unsigned short* __restrict__ xt)
{
    const unsigned i = blockIdx.x * 256u + threadIdx.x;   // 2,097,152 threads
    const int v  = i & 1023;
    const int t  = (i >> 10) & 511;
    const int mq = (i >> 19) & 3;
    const int m  = v >> 6;
    const int w  = (v & 63) ^ (m & 7);
    const int k0 = (w >> 2) * 32 + (w & 3) * 8;
    const int b  = mq * 16 + m;
    const float4* s = (const float4*)(x + ((size_t)b * Sd + t) * Hd + k0);
    const float4 u0 = s[0], u1 = s[1];
    bf16x8 o;
    unsigned* ou = (unsigned*)&o;
    ou[0] = cvt_pk_bf16(u0.x, u0.y); ou[1] = cvt_pk_bf16(u0.z, u0.w);
    ou[2] = cvt_pk_bf16(u1.x, u1.y); ou[3] = cvt_pk_bf16(u1.z, u1.w);
    ((bf16x8*)xt)[i] = o;
}

// ---------------- prep: zero h ring + flags, fill bias ----------------
__global__ __launch_bounds__(256) void prep_misc(
    const float* __restrict__ b_f, const float* __restrict__ b_b,
    unsigned char* __restrict__ ws)
{
    const unsigned i = blockIdx.x * 256u + threadIdx.x;   // 16,384 threads
    ((int4*)(ws + HBF_OFF))[i] = make_int4(0, 0, 0, 0);
    if (i < 4096) {
        const int d = i >> 11;
        const int n = i & 2047;
        const int g = n & 3;
        const int h = n >> 2;
        ((float*)(ws + BIAS_OFF))[i] = (d ? b_b : b_f)[g * Hd + h];
    }
    if (i < 512) ((unsigned*)(ws + FLG_OFF))[i] = 0u;
}

// ---------------- persistent BiLSTM ----------------
__global__ __launch_bounds__(512, 2) void lstm_persist(
    unsigned char* __restrict__ ws,
    float* __restrict__ out)              // [S,B,2H] ++ h_f[B,H] ++ h_b[B,H]
{
    const int blk   = blockIdx.x;         // 128 blocks
    const int g     = blk & 7;            // sync group -> XCD g (heuristic)
    const int d     = g & 1;
    const int mq    = g >> 1;             // batch quarter (16 batches)
    const int ng    = blk >> 3;           // 0..15 within group (128 gate-cols)
    const int tid   = threadIdx.x;
    const int wid   = tid >> 6;           // 0..7
    const int lane  = tid & 63;

    const bf16x8* uwt_v = (const bf16x8*)(ws + UWT_OFF);
    bf16x8*       hbfv  = (bf16x8*)(ws + HBF_OFF);
    const float*  biasp = (const float*)(ws + BIAS_OFF);
    unsigned*     flg   = (unsigned*)(ws + FLG_OFF) + (size_t)g * 64;
    const char*   xt    = (const char*)(ws + XT_OFF);

    __shared__ __align__(16) short  xs[8192];      // x tile, 1024 frags (16KB)
    __shared__ __align__(16) bf16x8 hs[1024];      // h slab (16KB)
    __shared__ __align__(16) float  gbuf[16 * 128];// preacts (8KB)
    __shared__ float hbuf[16 * 32];                // new h fp32 (2KB)

    const int nt = ng * 8 + wid;          // this wave's n-tile (16 cols)

    // ---- hoist this wave's B slice (K=1024 x N=16) into regs/AGPRs ----
    bf16x8 Bfrag[32];
    {
        const bf16x8* Bp = uwt_v + (size_t)((d * 128 + nt) * 32) * 64 + lane;
        #pragma unroll
        for (int kb = 0; kb < 32; ++kb) Bfrag[kb] = Bp[(size_t)kb * 64];
    }

    const int jloc = tid & 31;            // h-col within block (0..31)
    const int mloc = tid >> 5;            // batch row (0..15)
    const float* bias = biasp + d * 2048 + ng * 128 + jloc * 4;
    const float bf_ = bias[0], bg_ = bias[1], bi_ = bias[2], bo_ = bias[3];

    float c0 = 0.f;                       // c-state: 1 cell/thread
    const int r0 = lane & 15, q = lane >> 4, r07 = r0 & 7;
    const bf16x8* xv = (const bf16x8*)xs;
    char* xsb = (char*)xs;

    f32x4 xacc_e, xacc_o;
    bf16x8 hl0, hl1;                      // h slab staging regs

    auto stage_x = [&](int tn) {          // 2 gld_lds per thread (16KB tile)
        const char* tb = xt + ((size_t)(mq * 512 + tn) * 1024) * 16;
        gld_lds16(tb + (size_t)(wid * 64 + lane) * 16,
                  xsb + (size_t)(wid * 64) * 16);
        gld_lds16(tb + (size_t)(512 + wid * 64 + lane) * 16,
                  xsb + (size_t)(512 + wid * 64) * 16);
    };
    auto xmfma = [&]() {                  // x-part preacts from xs
        xacc_e = (f32x4){0.f, 0.f, 0.f, 0.f};
        xacc_o = (f32x4){0.f, 0.f, 0.f, 0.f};
        #pragma unroll
        for (int kb2 = 0; kb2 < 16; kb2 += 2) {
            const bf16x8 a0 = xv[r0 * 64 + (((kb2    ) * 4 + q) ^ r07)];
            const bf16x8 a1 = xv[r0 * 64 + (((kb2 + 1) * 4 + q) ^ r07)];
            xacc_e = __builtin_amdgcn_mfma_f32_16x16x32_bf16(a0, Bfrag[16 + kb2], xacc_e, 0, 0, 0);
            xacc_o = __builtin_amdgcn_mfma_f32_16x16x32_bf16(a1, Bfrag[17 + kb2], xacc_o, 0, 0, 0);
        }
    };
    auto load_h = [&](int p) {            // 2 x 16B sc0 loads (slab frag tid, tid+512)
        const bf16x8* hb = hbfv + (size_t)(p * 8 + g) * 1024;
        LDC16(hl0, hb + tid);
        LDC16(hl1, hb + tid + 512);
    };

    // ---- prologue: stage x(0), load h(0) (zeroed ring), x-MFMA, park h in LDS ----
    {
        const int t0 = d ? (Sd - 1) : 0;
        stage_x(t0);
        load_h(0);
        asm volatile("s_waitcnt vmcnt(0)" ::: "memory");
        __builtin_amdgcn_sched_barrier(0);
    }
    __syncthreads();
    xmfma();
    hs[tid] = hl0;
    hs[tid + 512] = hl1;

    for (int t = 0; t < Sd; ++t) {
        const int t_orig = d ? (Sd - 1 - t) : t;
        const int p1 = (t & 1) ^ 1;       // write parity

        // ---- top: hs ready after lgkm drain + barrier; issue x(t+1) stage ----
        lgkm_bar();
        if (t < Sd - 1) stage_x(d ? (Sd - 2 - t) : (t + 1));

        // ---- h-part MFMAs from LDS slab; even/odd K chains (ILP-2) ----
        f32x4 acc_e = xacc_e, acc_o = xacc_o;
        #pragma unroll
        for (int kb = 0; kb < 16; kb += 2) {
            acc_e = __builtin_amdgcn_mfma_f32_16x16x32_bf16(hs[kb * 64 + lane],
                                                            Bfrag[kb], acc_e, 0, 0, 0);
            acc_o = __builtin_amdgcn_mfma_f32_16x16x32_bf16(hs[(kb + 1) * 64 + lane],
                                                            Bfrag[kb + 1], acc_o, 0, 0, 0);
        }

        // ---- scatter preacts to LDS (C/D: m=(lane>>4)*4+r, n=lane&15) ----
        {
            const f32x4 pre = acc_e + acc_o;
            const int nl = wid * 16 + (lane & 15);
            const int mr = (lane >> 4) * 4;
            #pragma unroll
            for (int r = 0; r < 4; ++r) gbuf[(mr + r) * 128 + nl] = pre[r];
        }
        lgkm_bar();

        // ---- combine: 1 cell/thread ----
        float h0c;
        {
            const f32x4 ga = *(const f32x4*)&gbuf[mloc * 128 + jloc * 4];
            c0 = c0 * sigmoidf_(ga[0] + bf_) + tanhf_(ga[1] + bg_) * sigmoidf_(ga[2] + bi_);
            h0c = sigmoidf_(ga[3] + bo_) * tanhf_(c0);
            hbuf[mloc * 32 + jloc] = h0c;
        }
        lgkm_bar();

        if (t < Sd - 1) {
            // ---- producer (wave 0): pack -> sc0 store -> ack -> flag ----
            if (tid < 64) {
                const int b  = lane >> 2;          // 0..15
                const int jh = lane & 3;           // 8-col group
                const float* hp4 = &hbuf[b * 32 + jh * 8];
                bf16x8 v;
                unsigned* vu = (unsigned*)&v;
                vu[0] = cvt_pk_bf16(hp4[0], hp4[1]);
                vu[1] = cvt_pk_bf16(hp4[2], hp4[3]);
                vu[2] = cvt_pk_bf16(hp4[4], hp4[5]);
                vu[3] = cvt_pk_bf16(hp4[6], hp4[7]);
                // block ng produces exactly kb=ng slice; frag lane = b + jh*16
                bf16x8* hp = hbfv + (size_t)(p1 * 8 + g) * 1024 + ng * 64 + (b + jh * 16);
                asm volatile("global_store_dwordx4 %0, %1, off sc0"
                             :: "v"(hp), "v"(v) : "memory");
                asm volatile("s_waitcnt vmcnt(0)" ::: "memory");   // h in L2
                if (tid == 0) {
                    unsigned* fp = flg + ng;
                    const unsigned fv = (unsigned)(t + 1);
                    asm volatile("global_store_dword %0, %1, off sc0"
                                 :: "v"(fp), "v"(fv) : "memory");
                }
            }
            // ---- poll (all waves): 16 flags in one sc0 load + ballot, watchdog ----
            {
                const unsigned tgt = (unsigned)(t + 1);
                const unsigned* fp = flg + (lane & 15);
                int guard = 0;
                for (;;) {
                    unsigned v;
                    asm volatile("global_load_dword %0, %1, off sc0\n\t"
                                 "s_waitcnt vmcnt(0)"
                                 : "=v"(v) : "v"(fp) : "memory");
                    if (__ballot(v >= tgt) == ~0ull) break;
                    __builtin_amdgcn_s_sleep(1);
                    if (++guard > (1 << 13)) break;   // fail loud, never wedge
                }
                __builtin_amdgcn_sched_barrier(0);
            }
        }

        // ---- output stores (off the sync critical path) ----
        {
            const int b0 = mq * 16 + mloc;
            const int jg = ng * 32 + jloc;
            __builtin_nontemporal_store(
                h0c, out + ((size_t)t_orig * Bd + b0) * TWO_H + (size_t)d * Hd + jg);
            if (t == Sd - 1) {
                out[(size_t)Sd * Bd * TWO_H + (size_t)d * Bd * Hd
                    + (size_t)b0 * Hd + jg] = h0c;
            }
        }

        if (t == Sd - 1) break;

        // ---- issue h(t+1) slab loads (sc0, to regs) ----
        load_h(p1);

        // ---- xs(t+1) ready: own glds drained by poll's vmcnt(0); sync waves ----
        raw_bar();
        xmfma();                          // x-part preacts for t+1 (hides h RTT)

        // ---- park h slab into LDS for next top ----
        asm volatile("s_waitcnt vmcnt(0)" ::: "memory");
        __builtin_amdgcn_sched_barrier(0);
        hs[tid] = hl0;
        hs[tid + 512] = hl1;
    }
}

extern "C" void kernel_launch(void* const* d_in, const int* in_sizes, int n_in,
                              void* d_out, int out_size, void* d_ws, size_t ws_size,
                              hipStream_t stream) {
    const float* x   = (const float*)d_in[0];
    // d_in[1] = mask: all-ones by construction; unused.
    const float* U_f = (const float*)d_in[2];
    const float* W_f = (const float*)d_in[3];
    const float* b_f = (const float*)d_in[4];
    const float* U_b = (const float*)d_in[5];
    const float* W_b = (const float*)d_in[6];
    const float* b_b = (const float*)d_in[7];
    float* out = (float*)d_out;
    unsigned char* ws = (unsigned char*)d_ws;

    prep_weights<<<2048, 256, 0, stream>>>(U_f, W_f, U_b, W_b,
                                           (unsigned short*)(ws + UWT_OFF));
    prep_misc<<<64, 256, 0, stream>>>(b_f, b_b, ws);
    prep_x<<<8192, 256, 0, stream>>>(x, (unsigned short*)(ws + XT_OFF));
    lstm_persist<<<128, 512, 0, stream>>>(ws, out);
}

// Round 8
// 3184.430 us; speedup vs baseline: 133.1669x; 133.1669x over previous
//
#include <hip/hip_runtime.h>
#include <math.h>

// BiLSTM B=64, S=512, I=H=512, fp32 in/out.
// Gate order f,g,i,o:  c = c*sig(f) + tanh(g)*sig(i); h = sig(o)*tanh(c)
// mask all-ones => lengths==S, h_f = fwd[S-1], h_b = bwd[0].
//
// Round-10 design: persistent kernel, DATA-CARRIED freshness (no flags, no acks).
//   Round-7 falsified XCD-local L2 sync (sc0-only: 424ms, stale-L2). Round-6
//   (flag protocol @ L3, 2484us) kept. This round removes the flag machinery:
//   - ring depth 8; block zeros its own 1KB chunk of slot t+3 during step t.
//   - freshness = all 4 dwords of a 16B fragment nonzero (min4 != 0).
//     Torn writes read as partially-zero -> not fresh. True-zero fragment ->
//     watchdog exits with the loaded zeros = still correct (self-healing).
//   - visibility: fresh slot(t) => owner passed verify-vmcnt(0) of step t-1
//     which drained its zero-stores of slot(t+2) => any consumer load of
//     slot(t+1+) sees zero-or-fresh, never stale. (zero-3-ahead => no ack.)
//   - WAR on zeroing: lazy progress counters (fire-and-forget store; check
//     "all >= t-3" is auto-true given data-dependency lockstep; watchdog'd).
//   - producer path: pack -> sc0sc1 store -> progress store. Nothing else.
//   - consumer: h loads ARE the poll; verify loop reloads until fresh.
//   Everything else = round 6: Bfrag in regs, pre-swizzled x tiles +
//   global_load_lds, vmcnt(32)+barrier+xmfma overlap, gbuf combine.
//   Fallbacks by ws_size: flag protocol (round-6 exact) / noXT staging.

#define Sd 512
#define Bd 64
#define Hd 512
#define TWO_H 1024

typedef __attribute__((ext_vector_type(8))) short bf16x8;
typedef __attribute__((ext_vector_type(4))) float f32x4;

// ws layout (bytes) — PROTO0 (data-carried)
#define UWT_OFF   0u          // bf16 [2][128][32][64][8]  = 8,388,608 B
#define BIAS_OFF  8388608u    // f32  [2][2048]            = 16,384 B
#define RING_OFF  8404992u    // bf16 [8 slot][4 grp][2mt][16kb][64][8] = 1,048,576 B
#define PRG_OFF   9453568u    // int  [4 grp][32] progress (pad to 2048)
#define XT0_OFF   9455616u    // bf16 tiles = 33,554,432 B
#define WS_NEED0  (XT0_OFF + 33554432u)
// PROTO1 (round-6 flag protocol) reuses RING_OFF region:
#define HBF_OFF   8404992u    // bf16 [2p][2d][4mt][16kb][64][8] = 262,144 B
#define FLG_OFF   8667136u    // u32  [4 groups][64] flags
#define XT1_OFF   8668160u
#define WS_NEED1  (XT1_OFF + 33554432u)

__device__ __forceinline__ unsigned short f2bf(float f) {
    unsigned u = __float_as_uint(f);
    u += 0x7fffu + ((u >> 16) & 1u);   // round-to-nearest-even
    return (unsigned short)(u >> 16);
}
__device__ __forceinline__ float sigmoidf_(float v) { return 1.0f / (1.0f + __expf(-v)); }
__device__ __forceinline__ float tanhf_(float v) {
    const float e = __expf(2.0f * v);  // exact at +/-inf
    return 1.0f - 2.0f / (e + 1.0f);
}
__device__ __forceinline__ unsigned cvt_pk_bf16(float lo, float hi) {
    unsigned r;
    asm("v_cvt_pk_bf16_f32 %0, %1, %2" : "=v"(r) : "v"(lo), "v"(hi));
    return r;
}
__device__ __forceinline__ void gld_lds16(const void* g, void* l) {
    __builtin_amdgcn_global_load_lds(
        (const __attribute__((address_space(1))) void*)(g),
        (__attribute__((address_space(3))) void*)(l), 16, 0, 0);
}
__device__ __forceinline__ void raw_bar() {
    __builtin_amdgcn_sched_barrier(0);
    __builtin_amdgcn_s_barrier();
    __builtin_amdgcn_sched_barrier(0);
}
__device__ __forceinline__ void lgkm_bar() {
    asm volatile("s_waitcnt lgkmcnt(0)" ::: "memory");
    raw_bar();
}
__device__ __forceinline__ bool frag_ok(const bf16x8& f) {
    union { bf16x8 v; unsigned u[4]; } w; w.v = f;
    unsigned a = w.u[0] < w.u[1] ? w.u[0] : w.u[1];
    unsigned b = w.u[2] < w.u[3] ? w.u[2] : w.u[3];
    a = a < b ? a : b;
    return a != 0u;          // all 4 dwords nonzero
}

// 4 coherence-point 16B loads off one base (kb stride = 64 lanes * 16B = 1024B)
#define LDH4(d0, d1, d2, d3, base)                                          \
    asm volatile("global_load_dwordx4 %0, %4, off sc0 sc1\n\t"              \
                 "global_load_dwordx4 %1, %4, off offset:1024 sc0 sc1\n\t"  \
                 "global_load_dwordx4 %2, %4, off offset:2048 sc0 sc1\n\t"  \
                 "global_load_dwordx4 %3, %4, off offset:3072 sc0 sc1"      \
                 : "=&v"(d0), "=&v"(d1), "=&v"(d2), "=&v"(d3)               \
                 : "v"(base))

// ---------------- prep: weights -> swizzled bf16 B-operand layout ----------------
__global__ __launch_bounds__(256) void prep_weights(
    const float* __restrict__ U_f, const float* __restrict__ W_f,
    const float* __restrict__ U_b, const float* __restrict__ W_b,
    unsigned short* __restrict__ uwt)
{
    const unsigned i = blockIdx.x * 256u + threadIdx.x;   // 524,288 threads
    const int h   = i & 511;
    const int k8  = (i >> 9) & 63;
    const int g   = (i >> 15) & 3;
    const int mat = (i >> 17) & 1;
    const int d   = (i >> 18) & 1;

    const float* src = mat ? (d ? W_b : W_f) : (d ? U_b : U_f);
    src += (size_t)g * Hd * Hd + (size_t)(k8 * 8) * Hd + h;

    const int n    = h * 4 + g;
    const int nt   = n >> 4;
    const int lane = (n & 15) + ((mat * 64 + k8) & 3) * 16;
    const int kb   = mat * 16 + (k8 >> 2);

    bf16x8 v;
    #pragma unroll
    for (int j = 0; j < 8; ++j)
        v[j] = (short)f2bf(src[(size_t)j * Hd]);

    ((bf16x8*)uwt)[((d * 128 + nt) * 32 + kb) * 64 + lane] = v;
}

// ---------------- prep: x fp32 -> bf16 fragment-swizzled tiles ----------------
__global__ __launch_bounds__(256) void prep_x(
    const float* __restrict__ x, unsigned short* __restrict__ xt)
{
    const unsigned i = blockIdx.x * 256u + threadIdx.x;   // 2,097,152 threads
    const int v  = i & 2047;
    const int t  = (i >> 11) & 511;
    const int mh = (i >> 20) & 1;
    const int m  = v >> 6;
    const int w  = (v & 63) ^ (m & 7);
    const int k0 = (w >> 2) * 32 + (w & 3) * 8;
    const int b  = mh * 32 + m;
    const float4* s = (const float4*)(x + ((size_t)b * Sd + t) * Hd + k0);
    const float4 u0 = s[0], u1 = s[1];
    bf16x8 o;
    unsigned* ou = (unsigned*)&o;
    ou[0] = cvt_pk_bf16(u0.x, u0.y); ou[1] = cvt_pk_bf16(u0.z, u0.w);
    ou[2] = cvt_pk_bf16(u1.x, u1.y); ou[3] = cvt_pk_bf16(u1.z, u1.w);
    ((bf16x8*)xt)[i] = o;
}

// ---------------- prep: zero ring+progress (bounded), fill bias ----------------
__global__ __launch_bounds__(256) void prep_misc(
    const float* __restrict__ b_f, const float* __restrict__ b_b,
    unsigned char* __restrict__ ws, unsigned long long zero_bytes)
{
    const unsigned i = blockIdx.x * 256u + threadIdx.x;
    if ((unsigned long long)i * 16ull < zero_bytes)
        ((int4*)(ws + RING_OFF))[i] = make_int4(0, 0, 0, 0);
    if (i < 4096) {
        const int d = i >> 11;
        const int n = i & 2047;
        const int g = n & 3;
        const int h = n >> 2;
        ((float*)(ws + BIAS_OFF))[i] = (d ? b_b : b_f)[g * Hd + h];
    }
}

// ================= PROTO0: data-carried freshness persistent kernel =============
__global__ __launch_bounds__(256, 1) void lstm_data(
    unsigned char* __restrict__ ws,
    float* __restrict__ out)
{
    const int blk   = blockIdx.x;         // 128 blocks
    const int g     = blk & 3;            // group = (d, mhalf)
    const int d     = g & 1;
    const int mhalf = (g >> 1) & 1;
    const int ng    = blk >> 2;           // 0..31
    const int tid   = threadIdx.x;
    const int wid   = tid >> 6;
    const int lane  = tid & 63;

    const bf16x8* uwt_v = (const bf16x8*)(ws + UWT_OFF);
    bf16x8*       ring  = (bf16x8*)(ws + RING_OFF);  // [slot8][grp4][2048]
    int*          prg   = (int*)(ws + PRG_OFF) + g * 32;
    const float*  biasp = (const float*)(ws + BIAS_OFF);
    const char*   xt    = (const char*)(ws + XT0_OFF);

    __shared__ __align__(16) short xs[16384];      // 32KB linear x tile
    __shared__ __align__(16) float gbuf[32 * 64];  // preacts
    __shared__ float hbuf[32 * 16];                // new h fp32

    const int nt = ng * 4 + wid;

    bf16x8 Bfrag[32];
    {
        const bf16x8* Bp = uwt_v + (size_t)((d * 128 + nt) * 32) * 64 + lane;
        #pragma unroll
        for (int kb = 0; kb < 32; ++kb) Bfrag[kb] = Bp[(size_t)kb * 64];
    }

    const int jloc = tid & 15;
    const int mloc = tid >> 4;
    const float* bias = biasp + d * 2048 + ng * 64 + jloc * 4;
    const float bf_ = bias[0], bg_ = bias[1], bi_ = bias[2], bo_ = bias[3];

    float c0 = 0.f, c1 = 0.f;
    const int r0 = lane & 15, q = lane >> 4, r07 = r0 & 7;
    const bf16x8* xv = (const bf16x8*)xs;
    char* xsb = (char*)xs;

    f32x4 xacc0, xacc1;
    bf16x8 A0[16], A1[16];
    #pragma unroll
    for (int i = 0; i < 16; ++i) { A0[i] = (bf16x8)(short)0; A1[i] = (bf16x8)(short)0; }

    auto stage_x = [&](int tn) {
        const char* tb = xt + ((size_t)(mhalf * 512 + tn) * 2048) * 16;
        #pragma unroll
        for (int j = 0; j < 8; ++j) {
            const int chunk = wid * 8 + j;
            gld_lds16(tb + (size_t)chunk * 1024 + (size_t)lane * 16,
                      xsb + chunk * 1024);
        }
    };
    auto xmfma = [&]() {
        xacc0 = (f32x4){0.f, 0.f, 0.f, 0.f};
        xacc1 = (f32x4){0.f, 0.f, 0.f, 0.f};
        #pragma unroll
        for (int kb2 = 0; kb2 < 16; ++kb2) {
            const bf16x8 bfrag = Bfrag[16 + kb2];
            const int u0 = r0 * 64 + ((kb2 * 4 + q) ^ r07);
            const bf16x8 a0 = xv[u0];
            const bf16x8 a1 = xv[u0 + 1024];
            xacc0 = __builtin_amdgcn_mfma_f32_16x16x32_bf16(a0, bfrag, xacc0, 0, 0, 0);
            xacc1 = __builtin_amdgcn_mfma_f32_16x16x32_bf16(a1, bfrag, xacc1, 0, 0, 0);
        }
    };
    auto issue_h = [&](int slot) {
        const unsigned char* hb = (const unsigned char*)(ring
            + (size_t)((slot & 7) * 4 + g) * 2048 + lane);
        LDH4(A0[0],  A0[1],  A0[2],  A0[3],  hb);
        LDH4(A0[4],  A0[5],  A0[6],  A0[7],  hb + 4096);
        LDH4(A0[8],  A0[9],  A0[10], A0[11], hb + 8192);
        LDH4(A0[12], A0[13], A0[14], A0[15], hb + 12288);
        LDH4(A1[0],  A1[1],  A1[2],  A1[3],  hb + 16384);
        LDH4(A1[4],  A1[5],  A1[6],  A1[7],  hb + 20480);
        LDH4(A1[8],  A1[9],  A1[10], A1[11], hb + 24576);
        LDH4(A1[12], A1[13], A1[14], A1[15], hb + 28672);
    };

    // ---- prologue: stage x(0), x-preacts; h(0)=0 already in A regs ----
    {
        const int t0 = d ? (Sd - 1) : 0;
        stage_x(t0);
        asm volatile("s_waitcnt vmcnt(0)" ::: "memory");
        __builtin_amdgcn_sched_barrier(0);
    }
    __syncthreads();
    xmfma();

    for (int t = 0; t < Sd; ++t) {
        const int t_orig = d ? (Sd - 1 - t) : t;

        // ---- a: h-part MFMAs (A verified last step / zero at t=0) ----
        f32x4 acc0 = xacc0, acc1 = xacc1;
        #pragma unroll
        for (int kb = 0; kb < 16; ++kb) {
            acc0 = __builtin_amdgcn_mfma_f32_16x16x32_bf16(A0[kb], Bfrag[kb], acc0, 0, 0, 0);
            acc1 = __builtin_amdgcn_mfma_f32_16x16x32_bf16(A1[kb], Bfrag[kb], acc1, 0, 0, 0);
        }

        // ---- b: scatter preacts ----
        {
            const int nl = wid * 16 + (lane & 15);
            const int mr = (lane >> 4) * 4;
            #pragma unroll
            for (int r = 0; r < 4; ++r) gbuf[(mr + r) * 64 + nl] = acc0[r];
            #pragma unroll
            for (int r = 0; r < 4; ++r) gbuf[(16 + mr + r) * 64 + nl] = acc1[r];
        }
        lgkm_bar();

        // ---- c: combine ----
        float h0c, h1c;
        {
            const f32x4 ga = *(const f32x4*)&gbuf[mloc * 64 + jloc * 4];
            const f32x4 gb = *(const f32x4*)&gbuf[(mloc + 16) * 64 + jloc * 4];
            c0 = c0 * sigmoidf_(ga[0] + bf_) + tanhf_(ga[1] + bg_) * sigmoidf_(ga[2] + bi_);
            h0c = sigmoidf_(ga[3] + bo_) * tanhf_(c0);
            c1 = c1 * sigmoidf_(gb[0] + bf_) + tanhf_(gb[1] + bg_) * sigmoidf_(gb[2] + bi_);
            h1c = sigmoidf_(gb[3] + bo_) * tanhf_(c1);
        }

        if (t == Sd - 1) {
            const int b0 = mhalf * 32 + mloc;
            const int jg = ng * 16 + jloc;
            float* ob = out + (size_t)d * Hd + jg;
            __builtin_nontemporal_store(h0c, ob + ((size_t)t_orig * Bd + b0) * TWO_H);
            __builtin_nontemporal_store(h1c, ob + ((size_t)t_orig * Bd + b0 + 16) * TWO_H);
            float* hf = out + (size_t)Sd * Bd * TWO_H + (size_t)d * Bd * Hd + jg;
            hf[(size_t)b0 * Hd] = h0c;
            hf[(size_t)(b0 + 16) * Hd] = h1c;
            break;
        }

        hbuf[mloc * 16 + jloc] = h0c;
        hbuf[(mloc + 16) * 16 + jloc] = h1c;
        lgkm_bar();

        // ---- d: producer (wave 0): pack -> sc0sc1 store -> progress (no ack) ----
        if (wid == 0) {
            const int ml2 = lane >> 1;
            const int jh  = lane & 1;
            const int jb  = ng * 16 + jh * 8;
            const int kb  = jb >> 5;
            const int lq  = (jb >> 3) & 3;
            const int lh  = (ml2 & 15) + lq * 16;
            const int mtl = ml2 >> 4;
            const float* hp4 = &hbuf[ml2 * 16 + jh * 8];
            bf16x8 v;
            unsigned* vu = (unsigned*)&v;
            vu[0] = cvt_pk_bf16(hp4[0], hp4[1]);
            vu[1] = cvt_pk_bf16(hp4[2], hp4[3]);
            vu[2] = cvt_pk_bf16(hp4[4], hp4[5]);
            vu[3] = cvt_pk_bf16(hp4[6], hp4[7]);
            bf16x8* hp = ring + (size_t)(((t + 1) & 7) * 4 + g) * 2048
                       + (mtl * 16 + kb) * 64 + lh;
            asm volatile("global_store_dwordx4 %0, %1, off sc0 sc1"
                         :: "v"(hp), "v"(v) : "memory");
            if (lane == 0) {
                int* pp = prg + ng;
                const int pv = t + 1;
                asm volatile("global_store_dword %0, %1, off sc0 sc1"
                             :: "v"(pp), "v"(pv) : "memory");
            }
        }

        // ---- e: wave 1: WAR check (lazy) + zero own chunk of slot t+3 ----
        if (wid == 1) {
            {
                const int* pp = prg + (lane & 31);
                int guard = 0;
                for (;;) {
                    int v;
                    asm volatile("global_load_dword %0, %1, off sc0 sc1\n\t"
                                 "s_waitcnt vmcnt(0)"
                                 : "=v"(v) : "v"(pp) : "memory");
                    if (__ballot(v >= t - 3) == ~0ull) break;
                    __builtin_amdgcn_s_sleep(1);
                    if (++guard > (1 << 13)) break;   // fail loud, never wedge
                }
            }
            const int ml2 = lane >> 1;
            const int jh  = lane & 1;
            const int jb  = ng * 16 + jh * 8;
            const int kb  = jb >> 5;
            const int lq  = (jb >> 3) & 3;
            const int lh  = (ml2 & 15) + lq * 16;
            const int mtl = ml2 >> 4;
            bf16x8* zp = ring + (size_t)(((t + 3) & 7) * 4 + g) * 2048
                       + (mtl * 16 + kb) * 64 + lh;
            const bf16x8 z = (bf16x8)(short)0;
            asm volatile("global_store_dwordx4 %0, %1, off sc0 sc1"
                         :: "v"(zp), "v"(z) : "memory");
        }

        // ---- f: output stores ----
        {
            const int b0 = mhalf * 32 + mloc;
            const int jg = ng * 16 + jloc;
            float* ob = out + (size_t)d * Hd + jg;
            __builtin_nontemporal_store(h0c, ob + ((size_t)t_orig * Bd + b0) * TWO_H);
            __builtin_nontemporal_store(h1c, ob + ((size_t)t_orig * Bd + b0 + 16) * TWO_H);
        }

        // ---- g,h: stage x(t+1); issue h(t+1) loads ----
        stage_x(d ? (Sd - 2 - t) : (t + 1));
        issue_h(t + 1);

        // ---- i: drain glds (+stores), sync, x-MFMA (hides h RTT) ----
        asm volatile("s_waitcnt vmcnt(32)" ::: "memory");
        __builtin_amdgcn_sched_barrier(0);
        raw_bar();
        xmfma();

        // ---- j: verify freshness of h(t+1); reload laggards ----
        {
            int guard = 0;
            for (;;) {
                asm volatile("s_waitcnt vmcnt(0)" ::: "memory");
                __builtin_amdgcn_sched_barrier(0);
                bool ok = true;
                #pragma unroll
                for (int i = 0; i < 16; ++i) { ok &= frag_ok(A0[i]); ok &= frag_ok(A1[i]); }
                if (__ballot(ok) == ~0ull) break;
                if (++guard > (1 << 12)) break;   // self-healing / fail loud
                issue_h(t + 1);
            }
            __builtin_amdgcn_sched_barrier(0);
        }
    }
}

// ================= PROTO1: round-6 flag protocol (proven fallback) ==============
template<bool XT>
__global__ __launch_bounds__(256, 1) void lstm_flag(
    const float* __restrict__ x,
    unsigned char* __restrict__ ws,
    float* __restrict__ out)
{
    const int blk   = blockIdx.x;
    const int g     = blk & 3;
    const int d     = g & 1;
    const int mhalf = (g >> 1) & 1;
    const int ng    = blk >> 2;
    const int tid   = threadIdx.x;
    const int wid   = tid >> 6;
    const int lane  = tid & 63;

    const bf16x8* uwt_v = (const bf16x8*)(ws + UWT_OFF);
    bf16x8*       hbf_w = (bf16x8*)(ws + HBF_OFF);
    const float*  biasp = (const float*)(ws + BIAS_OFF);
    unsigned*     flg   = (unsigned*)(ws + FLG_OFF) + (size_t)g * 64;
    const char*   xt    = (const char*)(ws + XT1_OFF);

    __shared__ __align__(16) short xs[16640];
    __shared__ __align__(16) float gbuf[32 * 64];
    __shared__ float hbuf[32 * 16];

    const int nt  = ng * 4 + wid;
    const int mt0 = mhalf * 2;

    bf16x8 Bfrag[32];
    {
        const bf16x8* Bp = uwt_v + (size_t)((d * 128 + nt) * 32) * 64 + lane;
        #pragma unroll
        for (int kb = 0; kb < 32; ++kb) Bfrag[kb] = Bp[(size_t)kb * 64];
    }

    const int jloc = tid & 15;
    const int mloc = tid >> 4;
    const float* bias = biasp + d * 2048 + ng * 64 + jloc * 4;
    const float bf_ = bias[0], bg_ = bias[1], bi_ = bias[2], bo_ = bias[3];

    float c0 = 0.f, c1 = 0.f;
    const float4* x4 = (const float4*)x;
    const int r0 = lane & 15, q = lane >> 4, r07 = r0 & 7;
    const bf16x8* xv = (const bf16x8*)xs;
    char* xsb = (char*)xs;

    f32x4 xacc0, xacc1;
    bf16x8 A0[16], A1[16];

    auto stage_x = [&](int tn) {
        const char* tb = xt + ((size_t)(mhalf * 512 + tn) * 2048) * 16;
        #pragma unroll
        for (int j = 0; j < 8; ++j) {
            const int chunk = wid * 8 + j;
            gld_lds16(tb + (size_t)chunk * 1024 + (size_t)lane * 16,
                      xsb + chunk * 1024);
        }
    };
    auto stage_x_conv = [&](int tn) {
        for (int i = tid; i < 32 * 128; i += 256) {
            const int m  = i >> 7;
            const int c4 = i & 127;
            const int b  = mhalf * 32 + m;
            const float4 v = x4[((size_t)b * Sd + tn) * 128 + c4];
            short* p = xs + m * 520 + c4 * 4;
            *(uint2*)p = make_uint2(cvt_pk_bf16(v.x, v.y), cvt_pk_bf16(v.z, v.w));
        }
    };
    auto xmfma = [&]() {
        xacc0 = (f32x4){0.f, 0.f, 0.f, 0.f};
        xacc1 = (f32x4){0.f, 0.f, 0.f, 0.f};
        #pragma unroll
        for (int kb2 = 0; kb2 < 16; ++kb2) {
            const bf16x8 bfrag = Bfrag[16 + kb2];
            int u0, u1;
            if constexpr (XT) { u0 = r0 * 64 + ((kb2 * 4 + q) ^ r07); u1 = u0 + 1024; }
            else              { u0 = r0 * 65 + kb2 * 4 + q;           u1 = u0 + 16 * 65; }
            const bf16x8 a0 = xv[u0];
            const bf16x8 a1 = xv[u1];
            xacc0 = __builtin_amdgcn_mfma_f32_16x16x32_bf16(a0, bfrag, xacc0, 0, 0, 0);
            xacc1 = __builtin_amdgcn_mfma_f32_16x16x32_bf16(a1, bfrag, xacc1, 0, 0, 0);
        }
    };
    auto issue_h = [&](int p) {
        const unsigned char* hb = ws + HBF_OFF
            + ((size_t)(((p * 2 + d) * 4 + mt0) * 16) * 64 + lane) * 16;
        LDH4(A0[0],  A0[1],  A0[2],  A0[3],  hb);
        LDH4(A0[4],  A0[5],  A0[6],  A0[7],  hb + 4096);
        LDH4(A0[8],  A0[9],  A0[10], A0[11], hb + 8192);
        LDH4(A0[12], A0[13], A0[14], A0[15], hb + 12288);
        LDH4(A1[0],  A1[1],  A1[2],  A1[3],  hb + 16384);
        LDH4(A1[4],  A1[5],  A1[6],  A1[7],  hb + 20480);
        LDH4(A1[8],  A1[9],  A1[10], A1[11], hb + 24576);
        LDH4(A1[12], A1[13], A1[14], A1[15], hb + 28672);
    };

    {
        const int t0 = d ? (Sd - 1) : 0;
        if constexpr (XT) {
            stage_x(t0);
            asm volatile("s_waitcnt vmcnt(0)" ::: "memory");
        } else {
            stage_x_conv(t0);
        }
    }
    __syncthreads();
    xmfma();
    issue_h(0);

    for (int t = 0; t < Sd; ++t) {
        const int t_orig = d ? (Sd - 1 - t) : t;
        const int p1 = (t & 1) ^ 1;

        if constexpr (XT) {
            raw_bar();
            const int tn = d ? ((Sd - 2 - t) > 0 ? (Sd - 2 - t) : 0)
                             : ((t + 1) < (Sd - 1) ? (t + 1) : (Sd - 1));
            stage_x(tn);
        }

        f32x4 acc0 = xacc0, acc1 = xacc1;
        if constexpr (XT) asm volatile("s_waitcnt vmcnt(24)" ::: "memory");
        else              asm volatile("s_waitcnt vmcnt(16)" ::: "memory");
        __builtin_amdgcn_sched_barrier(0);
        #pragma unroll
        for (int kb = 0; kb < 16; ++kb)
            acc0 = __builtin_amdgcn_mfma_f32_16x16x32_bf16(A0[kb], Bfrag[kb], acc0, 0, 0, 0);
        __builtin_amdgcn_sched_barrier(0);
        if constexpr (XT) asm volatile("s_waitcnt vmcnt(8)" ::: "memory");
        else              asm volatile("s_waitcnt vmcnt(0)" ::: "memory");
        __builtin_amdgcn_sched_barrier(0);
        #pragma unroll
        for (int kb = 0; kb < 16; ++kb)
            acc1 = __builtin_amdgcn_mfma_f32_16x16x32_bf16(A1[kb], Bfrag[kb], acc1, 0, 0, 0);

        {
            const int nl = wid * 16 + (lane & 15);
            const int mr = (lane >> 4) * 4;
            #pragma unroll
            for (int r = 0; r < 4; ++r) gbuf[(mr + r) * 64 + nl] = acc0[r];
            #pragma unroll
            for (int r = 0; r < 4; ++r) gbuf[(16 + mr + r) * 64 + nl] = acc1[r];
        }
        lgkm_bar();

        float h0c, h1c;
        {
            const f32x4 ga = *(const f32x4*)&gbuf[mloc * 64 + jloc * 4];
            const f32x4 gb = *(const f32x4*)&gbuf[(mloc + 16) * 64 + jloc * 4];
            c0 = c0 * sigmoidf_(ga[0] + bf_) + tanhf_(ga[1] + bg_) * sigmoidf_(ga[2] + bi_);
            h0c = sigmoidf_(ga[3] + bo_) * tanhf_(c0);
            c1 = c1 * sigmoidf_(gb[0] + bf_) + tanhf_(gb[1] + bg_) * sigmoidf_(gb[2] + bi_);
            h1c = sigmoidf_(gb[3] + bo_) * tanhf_(c1);
            hbuf[mloc * 16 + jloc] = h0c;
            hbuf[(mloc + 16) * 16 + jloc] = h1c;
        }
        lgkm_bar();

        if (t < Sd - 1) {
            if (tid < 64) {
                const int ml2 = tid >> 1;
                const int jh  = tid & 1;
                const int b   = mhalf * 32 + ml2;
                const int jb  = ng * 16 + jh * 8;
                const int kb  = jb >> 5;
                const int lq  = (jb >> 3) & 3;
                const int lh  = (b & 15) + lq * 16;
                const int mt  = b >> 4;
                const float* hp4 = &hbuf[ml2 * 16 + jh * 8];
                bf16x8 v;
                unsigned* vu = (unsigned*)&v;
                vu[0] = cvt_pk_bf16(hp4[0], hp4[1]);
                vu[1] = cvt_pk_bf16(hp4[2], hp4[3]);
                vu[2] = cvt_pk_bf16(hp4[4], hp4[5]);
                vu[3] = cvt_pk_bf16(hp4[6], hp4[7]);
                bf16x8* hp = hbf_w + (size_t)(((p1 * 2 + d) * 4 + mt) * 16 + kb) * 64 + lh;
                asm volatile("global_store_dwordx4 %0, %1, off sc0 sc1"
                             :: "v"(hp), "v"(v) : "memory");
                asm volatile("s_waitcnt vmcnt(0)" ::: "memory");
                if (tid == 0) {
                    unsigned* fp = flg + ng;
                    const unsigned fv = (unsigned)(t + 1);
                    asm volatile("global_store_dword %0, %1, off sc0 sc1"
                                 :: "v"(fp), "v"(fv) : "memory");
                }
            }
            {
                const unsigned tgt = (unsigned)(t + 1);
                const unsigned* fp = flg + (lane & 31);
                int guard = 0;
                for (;;) {
                    unsigned v;
                    asm volatile("global_load_dword %0, %1, off sc0 sc1\n\t"
                                 "s_waitcnt vmcnt(0)"
                                 : "=v"(v) : "v"(fp) : "memory");
                    if (__ballot(v >= tgt) == ~0ull) break;
                    __builtin_amdgcn_s_sleep(1);
                    if (++guard > (1 << 15)) break;
                }
                __builtin_amdgcn_sched_barrier(0);
            }
        }

        {
            const int b0 = mhalf * 32 + mloc;
            const int jg = ng * 16 + jloc;
            float* ob = out + (size_t)d * Hd + jg;
            __builtin_nontemporal_store(h0c, ob + ((size_t)t_orig * Bd + b0) * TWO_H);
            __builtin_nontemporal_store(h1c, ob + ((size_t)t_orig * Bd + b0 + 16) * TWO_H);
            if (t == Sd - 1) {
                float* hf = out + (size_t)Sd * Bd * TWO_H + (size_t)d * Bd * Hd + jg;
                hf[(size_t)b0 * Hd] = h0c;
                hf[(size_t)(b0 + 16) * Hd] = h1c;
            }
        }

        if (t == Sd - 1) break;

        issue_h(p1);

        if constexpr (XT) {
            asm volatile("s_waitcnt vmcnt(32)" ::: "memory");
            __builtin_amdgcn_sched_barrier(0);
            raw_bar();
        } else {
            const int tn = d ? (Sd - 2 - t) : (t + 1);
            stage_x_conv(tn);
            lgkm_bar();
        }
        xmfma();
    }
}

extern "C" void kernel_launch(void* const* d_in, const int* in_sizes, int n_in,
                              void* d_out, int out_size, void* d_ws, size_t ws_size,
                              hipStream_t stream) {
    const float* x   = (const float*)d_in[0];
    // d_in[1] = mask: all-ones by construction; unused.
    const float* U_f = (const float*)d_in[2];
    const float* W_f = (const float*)d_in[3];
    const float* b_f = (const float*)d_in[4];
    const float* U_b = (const float*)d_in[5];
    const float* W_b = (const float*)d_in[6];
    const float* b_b = (const float*)d_in[7];
    float* out = (float*)d_out;
    unsigned char* ws = (unsigned char*)d_ws;

    prep_weights<<<2048, 256, 0, stream>>>(U_f, W_f, U_b, W_b,
                                           (unsigned short*)(ws + UWT_OFF));

    if (ws_size >= (size_t)WS_NEED0) {
        // zero ring + progress (1,050,624 B)
        prep_misc<<<260, 256, 0, stream>>>(b_f, b_b, ws, 1050624ull);
        prep_x<<<8192, 256, 0, stream>>>(x, (unsigned short*)(ws + XT0_OFF));
        lstm_data<<<128, 256, 0, stream>>>(ws, out);
    } else if (ws_size >= (size_t)WS_NEED1) {
        prep_misc<<<66, 256, 0, stream>>>(b_f, b_b, ws, 264192ull); // HBF+FLG
        prep_x<<<8192, 256, 0, stream>>>(x, (unsigned short*)(ws + XT1_OFF));
        lstm_flag<true><<<128, 256, 0, stream>>>(x, ws, out);
    } else {
        prep_misc<<<66, 256, 0, stream>>>(b_f, b_b, ws, 264192ull);
        lstm_flag<false><<<128, 256, 0, stream>>>(x, ws, out);
    }
}